// Round 2
// baseline (222.698 us; speedup 1.0000x reference)
//
#include <hip/hip_runtime.h>

typedef unsigned int u32;

constexpr int B = 128, NN = 400, FEAT = 256, DEG = 64;
constexpr int N = B * NN;          // 51200
constexpr int E = B * NN * DEG;    // 3276800
constexpr int EPG = NN * DEG;      // 25600 edges per graph
constexpr int SPL = 4;             // edge splits per graph
constexpr int EPS = EPG / SPL;     // 6400 edges per split-block

__device__ __forceinline__ float lrelu(float t) { return t > 0.f ? t : 0.01f * t; }

// K1: h0 = leaky_relu(x @ fc1_w.T + fc1_b)   [128,400]
// grid 256 (2 per batch row), block 256
__global__ void k_h0(const float* __restrict__ x, const float* __restrict__ fc1w,
                     const float* __restrict__ fc1b, float* __restrict__ h0g) {
    int b  = blockIdx.x >> 1;
    int nb = (blockIdx.x & 1) * 200;
    __shared__ float xs[FEAT];
    if (threadIdx.x < FEAT) xs[threadIdx.x] = x[b * FEAT + threadIdx.x];
    __syncthreads();
    if (threadIdx.x < 200) {
        int n = nb + threadIdx.x;
        const float4* w4 = reinterpret_cast<const float4*>(fc1w + n * FEAT);
        float s = 0.f;
        #pragma unroll 4
        for (int k4 = 0; k4 < FEAT / 4; ++k4) {
            float4 p = w4[k4];
            const float* xk = xs + k4 * 4;
            s += p.x * xk[0] + p.y * xk[1] + p.z * xk[2] + p.w * xk[3];
        }
        h0g[b * NN + n] = lrelu(s + fc1b[n]);
    }
}

// K2: conv1 edge aggregation (scalar channel), LDS partials -> global partial slots
// grid 512 (128 graphs x 4 splits), block 256
__global__ void k_conv1(const int* __restrict__ ei, const float* __restrict__ ea,
                        const float* __restrict__ h0g,
                        float* __restrict__ agg1p, float* __restrict__ cntp) {
    int b = blockIdx.x >> 2, sp = blockIdx.x & 3;
    __shared__ float a1[NN];
    __shared__ float ct[NN];
    for (int i = threadIdx.x; i < NN; i += 256) { a1[i] = 0.f; ct[i] = 0.f; }
    __syncthreads();
    int ebase = b * EPG + sp * EPS;
    const float* h0b = h0g + b * NN;
    int boff = b * NN;
    for (int e = ebase + (int)threadIdx.x; e < ebase + EPS; e += 256) {
        int s = ei[e] - boff;
        int d = ei[E + e] - boff;
        float w = ea[e];
        atomicAdd(&a1[d], w * h0b[s]);
        atomicAdd(&ct[d], 1.0f);
    }
    __syncthreads();
    for (int i = threadIdx.x; i < NN; i += 256) {
        agg1p[sp * N + boff + i] = a1[i];
        cntp[sp * N + boff + i]  = ct[i];
    }
}

// K3: h1[n][8] = leaky(agg1/cnt * Wrel1 + brel1 + h0 * Wroot1); also combined cnt
// grid 200, block 256
__global__ void k_h1(const float* __restrict__ agg1p, const float* __restrict__ cntp,
                     const float* __restrict__ h0g,
                     const float* __restrict__ Wr1, const float* __restrict__ br1,
                     const float* __restrict__ Wo1,
                     float* __restrict__ h1g, float* __restrict__ cntg) {
    int n = blockIdx.x * 256 + threadIdx.x;
    float a = 0.f, c = 0.f;
    #pragma unroll
    for (int sp = 0; sp < SPL; ++sp) { a += agg1p[sp * N + n]; c += cntp[sp * N + n]; }
    cntg[n] = c;
    a /= fmaxf(c, 1.f);
    float h0 = h0g[n];
    float v[8];
    #pragma unroll
    for (int k = 0; k < 8; ++k)
        v[k] = lrelu(a * Wr1[k] + br1[k] + h0 * Wo1[k]);
    float4* o = reinterpret_cast<float4*>(h1g + n * 8);
    o[0] = make_float4(v[0], v[1], v[2], v[3]);
    o[1] = make_float4(v[4], v[5], v[6], v[7]);
}

// K4: conv2 edge aggregation (8 channels, 8 lanes per edge), LDS partials
// grid 512, block 256
__global__ void k_conv2(const int* __restrict__ ei, const float* __restrict__ ea,
                        const float* __restrict__ h1g, float* __restrict__ agg2p) {
    int b = blockIdx.x >> 2, sp = blockIdx.x & 3;
    __shared__ float a2[NN * 8];
    for (int i = threadIdx.x; i < NN * 8; i += 256) a2[i] = 0.f;
    __syncthreads();
    int c  = threadIdx.x & 7;
    int eo = threadIdx.x >> 3;    // 0..31
    int ebase = b * EPG + sp * EPS;
    int boff = b * NN;
    const float* h1b = h1g + (size_t)boff * 8;
    for (int e = ebase + eo; e < ebase + EPS; e += 32) {
        int s = ei[e] - boff;
        int d = ei[E + e] - boff;
        float w = ea[e];
        atomicAdd(&a2[d * 8 + c], w * h1b[s * 8 + c]);
    }
    __syncthreads();
    for (int i = threadIdx.x; i < NN * 8; i += 256)
        agg2p[sp * (8 * N) + boff * 8 + i] = a2[i];
}

// K5: out[b,i,j] = sigmoid(0.5*(z_i.m_j + z_j.m_i + bb[i] + bb[j]))
// z = [agg2/cnt (8), h1 (8)], m_j = [Wrel2[j,:], Wroot2[j,:]]
// grid 512 (128 graphs x 4 row-blocks of 100), block 512
__global__ void __launch_bounds__(512, 4)
k_out(const float* __restrict__ h1g, const float* __restrict__ agg2p,
      const float* __restrict__ cntg,
      const float* __restrict__ Wr2, const float* __restrict__ br2,
      const float* __restrict__ Wo2, float* __restrict__ out) {
    int b = blockIdx.x >> 2, rb = blockIdx.x & 3;
    __shared__ alignas(16) float Zt[16 * NN];
    __shared__ alignas(16) float Mt[16 * NN];
    __shared__ float bbs[NN];

    int j = threadIdx.x;
    if (j < NN) {
        int n = b * NN + j;
        float cm = fmaxf(cntg[n], 1.f);
        float4 sA = make_float4(0, 0, 0, 0), sB = make_float4(0, 0, 0, 0);
        #pragma unroll
        for (int sp = 0; sp < SPL; ++sp) {
            const float4* ap = reinterpret_cast<const float4*>(agg2p + (size_t)sp * 8 * N + (size_t)n * 8);
            float4 p0 = ap[0], p1 = ap[1];
            sA.x += p0.x; sA.y += p0.y; sA.z += p0.z; sA.w += p0.w;
            sB.x += p1.x; sB.y += p1.y; sB.z += p1.z; sB.w += p1.w;
        }
        float inv = 1.f / cm;
        Zt[0 * NN + j] = sA.x * inv; Zt[1 * NN + j] = sA.y * inv;
        Zt[2 * NN + j] = sA.z * inv; Zt[3 * NN + j] = sA.w * inv;
        Zt[4 * NN + j] = sB.x * inv; Zt[5 * NN + j] = sB.y * inv;
        Zt[6 * NN + j] = sB.z * inv; Zt[7 * NN + j] = sB.w * inv;
        const float4* hv = reinterpret_cast<const float4*>(h1g + (size_t)n * 8);
        float4 h0v = hv[0], h1v = hv[1];
        Zt[ 8 * NN + j] = h0v.x; Zt[ 9 * NN + j] = h0v.y;
        Zt[10 * NN + j] = h0v.z; Zt[11 * NN + j] = h0v.w;
        Zt[12 * NN + j] = h1v.x; Zt[13 * NN + j] = h1v.y;
        Zt[14 * NN + j] = h1v.z; Zt[15 * NN + j] = h1v.w;
        const float* wr = Wr2 + j * 8;
        const float* wo = Wo2 + j * 8;
        #pragma unroll
        for (int k = 0; k < 8; ++k) {
            Mt[k * NN + j]       = wr[k];
            Mt[(8 + k) * NN + j] = wo[k];
        }
        bbs[j] = br2[j];
    }
    __syncthreads();

    for (int t = threadIdx.x; t < 25 * 50; t += 512) {
        int ti = t % 25, tj = t / 25;
        int i0 = rb * 100 + ti * 4;
        int j0 = tj * 8;
        float acc[4][8];
        #pragma unroll
        for (int r = 0; r < 4; ++r)
            #pragma unroll
            for (int cc = 0; cc < 8; ++cc) acc[r][cc] = 0.f;

        #pragma unroll
        for (int k = 0; k < 16; ++k) {
            const float* zr = Zt + k * NN;
            const float* mr = Mt + k * NN;
            float4 az  = *reinterpret_cast<const float4*>(zr + i0);
            float4 am  = *reinterpret_cast<const float4*>(mr + i0);
            float4 bz0 = *reinterpret_cast<const float4*>(zr + j0);
            float4 bz1 = *reinterpret_cast<const float4*>(zr + j0 + 4);
            float4 bm0 = *reinterpret_cast<const float4*>(mr + j0);
            float4 bm1 = *reinterpret_cast<const float4*>(mr + j0 + 4);
            float ar[4]  = {az.x, az.y, az.z, az.w};
            float amr[4] = {am.x, am.y, am.z, am.w};
            float bzv[8] = {bz0.x, bz0.y, bz0.z, bz0.w, bz1.x, bz1.y, bz1.z, bz1.w};
            float bmv[8] = {bm0.x, bm0.y, bm0.z, bm0.w, bm1.x, bm1.y, bm1.z, bm1.w};
            #pragma unroll
            for (int r = 0; r < 4; ++r)
                #pragma unroll
                for (int cc = 0; cc < 8; ++cc)
                    acc[r][cc] += ar[r] * bmv[cc] + amr[r] * bzv[cc];
        }

        float bi[4], bj[8];
        #pragma unroll
        for (int r = 0; r < 4; ++r) bi[r] = bbs[i0 + r];
        #pragma unroll
        for (int cc = 0; cc < 8; ++cc) bj[cc] = bbs[j0 + cc];

        size_t obase = (size_t)b * NN * NN;
        #pragma unroll
        for (int r = 0; r < 4; ++r) {
            float vout[8];
            #pragma unroll
            for (int cc = 0; cc < 8; ++cc) {
                float xv = 0.5f * (acc[r][cc] + bi[r] + bj[cc]);
                vout[cc] = 1.f / (1.f + __expf(-xv));
            }
            float* op = out + obase + (size_t)(i0 + r) * NN + j0;
            *reinterpret_cast<float4*>(op)     = make_float4(vout[0], vout[1], vout[2], vout[3]);
            *reinterpret_cast<float4*>(op + 4) = make_float4(vout[4], vout[5], vout[6], vout[7]);
        }
    }
}

extern "C" void kernel_launch(void* const* d_in, const int* in_sizes, int n_in,
                              void* d_out, int out_size, void* d_ws, size_t ws_size,
                              hipStream_t stream) {
    const float* x    = (const float*)d_in[0];
    const int*   ei   = (const int*)d_in[1];
    const float* ea   = (const float*)d_in[2];
    const float* fc1w = (const float*)d_in[3];
    const float* fc1b = (const float*)d_in[4];
    const float* Wr1  = (const float*)d_in[5];
    const float* br1  = (const float*)d_in[6];
    const float* Wo1  = (const float*)d_in[7];
    const float* Wr2  = (const float*)d_in[8];
    const float* br2  = (const float*)d_in[9];
    const float* Wo2  = (const float*)d_in[10];
    float* out = (float*)d_out;

    float* ws    = (float*)d_ws;
    float* h0g   = ws;             // N
    float* cntg  = ws + N;         // N
    float* h1g   = ws + 2 * N;     // 8N
    float* agg1p = ws + 10 * N;    // 4N
    float* cntp  = ws + 14 * N;    // 4N
    float* agg2p = ws + 18 * N;    // 32N  (total 50N floats = 10.24 MB)

    hipLaunchKernelGGL(k_h0,    dim3(256), dim3(256), 0, stream, x, fc1w, fc1b, h0g);
    hipLaunchKernelGGL(k_conv1, dim3(512), dim3(256), 0, stream, ei, ea, h0g, agg1p, cntp);
    hipLaunchKernelGGL(k_h1,    dim3(200), dim3(256), 0, stream, agg1p, cntp, h0g, Wr1, br1, Wo1, h1g, cntg);
    hipLaunchKernelGGL(k_conv2, dim3(512), dim3(256), 0, stream, ei, ea, h1g, agg2p);
    hipLaunchKernelGGL(k_out,   dim3(512), dim3(512), 0, stream, h1g, agg2p, cntg, Wr2, br2, Wo2, out);
}